// Round 3
// baseline (461.117 us; speedup 1.0000x reference)
//
#include <hip/hip_runtime.h>
#include <stdint.h>

// Pipeline: x(f32)->bf16; W->bf16 B^T layout (Wq pre-scaled by 1/8);
// QKV GEMM (MFMA 16x16x32 bf16, 128x128 tile, BK=64, global_load_lds + XOR swizzle);
// causal flash attention (BM=64/4 waves, BN=64 keys/iter, online softmax);
// proj GEMM + bias -> f32 out.

typedef __attribute__((ext_vector_type(8))) short bf16x8;
typedef __attribute__((ext_vector_type(4))) float f32x4;
typedef unsigned short ushort_t;

#define MFMA16(a, b, c) __builtin_amdgcn_mfma_f32_16x16x32_bf16(a, b, c, 0, 0, 0)

__device__ __forceinline__ ushort_t f2bf(float x) {
    union { float f; uint32_t u; } v; v.f = x;
    uint32_t r = v.u + 0x7fffu + ((v.u >> 16) & 1u);
    return (ushort_t)(r >> 16);
}

__device__ __forceinline__ void gload_lds16(const void* g, void* l) {
    __builtin_amdgcn_global_load_lds(
        (const __attribute__((address_space(1))) unsigned int*)g,
        (__attribute__((address_space(3))) unsigned int*)l, 16, 0, 0);
}

// ---------------- convert kernels ----------------
__global__ __launch_bounds__(256) void k_convert_x(const float* __restrict__ x,
                                                   ushort_t* __restrict__ xb) {
    const size_t n = (size_t)8 * 2048 * 512;
    const size_t stride = (size_t)gridDim.x * 256 * 4;
    for (size_t i = ((size_t)blockIdx.x * 256 + threadIdx.x) * 4; i < n; i += stride) {
        float4 f = *(const float4*)(x + i);
        uint2 o;
        o.x = (uint32_t)f2bf(f.x) | ((uint32_t)f2bf(f.y) << 16);
        o.y = (uint32_t)f2bf(f.z) | ((uint32_t)f2bf(f.w) << 16);
        *(uint2*)(xb + i) = o;
    }
}

// wqkv[3][512][512]: row n=h*64+d, col k=c, B^T layout. wp[512][512]: wp[n][k]=Wproj[k][n].
__global__ __launch_bounds__(256) void k_convert_w(const float* __restrict__ Wq,
                                                   const float* __restrict__ Wk,
                                                   const float* __restrict__ Wv,
                                                   const float* __restrict__ Wp,
                                                   ushort_t* __restrict__ wqkv,
                                                   ushort_t* __restrict__ wp) {
    int i = blockIdx.x * 256 + threadIdx.x;  // 0 .. 1048575
    if (i < 3 * 512 * 512) {
        int which = i >> 18;
        int r = i & 262143;
        int n = r >> 9, k = r & 511;
        int h = n >> 6, d = n & 63;
        const float* W = which == 0 ? Wq : (which == 1 ? Wk : Wv);
        float val = W[((size_t)h * 512 + k) * 64 + d];
        if (which == 0) val *= 0.125f;  // fold 1/sqrt(D) into q
        wqkv[i] = f2bf(val);
    } else {
        int r = i - 3 * 512 * 512;
        int n = r >> 9, k = r & 511;
        wp[r] = f2bf(Wp[(size_t)k * 512 + n]);
    }
}

// ---------------- shared 128x128 GEMM tile (BK=64) ----------------
// A [M][K] row-major bf16, Bt [N][K] row-major bf16 (i.e. B transposed).
// LDS linear dest via global_load_lds; 16B-granule XOR swizzle (sub ^ (row&7)) applied
// on the GLOBAL source and again on the ds_read address (both-sides rule, catalog #21).
template <int KDIM>
__device__ __forceinline__ void gemm_tile_128(const ushort_t* __restrict__ A,
                                              const ushort_t* __restrict__ Bt,
                                              int m0, int n0,
                                              ushort_t* As, ushort_t* Bs,
                                              f32x4 (&acc)[4][4]) {
    const int tid = threadIdx.x;
    const int wave = tid >> 6, lane = tid & 63;
    const int wm = (wave >> 1) * 64, wn = (wave & 1) * 64;
    for (int k0 = 0; k0 < KDIM; k0 += 64) {
        __syncthreads();
#pragma unroll
        for (int i = 0; i < 4; i++) {
            int base = wave * 4096 + i * 1024;
            int bb = base + lane * 16;
            int row = bb >> 7;
            int sub = (bb >> 4) & 7;
            int swz = (sub ^ (row & 7)) << 4;
            gload_lds16((const char*)(A + (size_t)(m0 + row) * KDIM + k0) + swz,
                        (char*)As + base);
        }
#pragma unroll
        for (int i = 0; i < 4; i++) {
            int base = wave * 4096 + i * 1024;
            int bb = base + lane * 16;
            int row = bb >> 7;
            int sub = (bb >> 4) & 7;
            int swz = (sub ^ (row & 7)) << 4;
            gload_lds16((const char*)(Bt + (size_t)(n0 + row) * KDIM + k0) + swz,
                        (char*)Bs + base);
        }
        __syncthreads();
        bf16x8 af[4][2], bf[4][2];
#pragma unroll
        for (int mt = 0; mt < 4; mt++)
#pragma unroll
            for (int ks = 0; ks < 2; ks++) {
                int row = wm + mt * 16 + (lane & 15);
                int sub = ks * 4 + (lane >> 4);
                af[mt][ks] = *(const bf16x8*)((const char*)As + row * 128 +
                                              ((sub ^ (row & 7)) << 4));
            }
#pragma unroll
        for (int nt = 0; nt < 4; nt++)
#pragma unroll
            for (int ks = 0; ks < 2; ks++) {
                int row = wn + nt * 16 + (lane & 15);
                int sub = ks * 4 + (lane >> 4);
                bf[nt][ks] = *(const bf16x8*)((const char*)Bs + row * 128 +
                                              ((sub ^ (row & 7)) << 4));
            }
#pragma unroll
        for (int mt = 0; mt < 4; mt++)
#pragma unroll
            for (int nt = 0; nt < 4; nt++)
#pragma unroll
                for (int ks = 0; ks < 2; ks++)
                    acc[mt][nt] = MFMA16(af[mt][ks], bf[nt][ks], acc[mt][nt]);
    }
}

// ---------------- QKV projection GEMM ----------------
__global__ __launch_bounds__(256) void k_gemm_qkv(const ushort_t* __restrict__ xb,
                                                  const ushort_t* __restrict__ wqkv,
                                                  ushort_t* __restrict__ qo,
                                                  ushort_t* __restrict__ ko,
                                                  ushort_t* __restrict__ vo) {
    __shared__ __align__(16) ushort_t As[128 * 64];
    __shared__ __align__(16) ushort_t Bs[128 * 64];
    const int m0 = blockIdx.x * 128;
    const int n0g = blockIdx.y * 128;  // 0..1535
    f32x4 acc[4][4] = {};
    gemm_tile_128<512>(xb, wqkv, m0, n0g, As, Bs, acc);
    const int tid = threadIdx.x, wave = tid >> 6, lane = tid & 63;
    const int wm = (wave >> 1) * 64, wn = (wave & 1) * 64;
    const int which = n0g >> 9;
    ushort_t* outp = which == 0 ? qo : (which == 1 ? ko : vo);
    const int n0 = n0g & 511;
#pragma unroll
    for (int mt = 0; mt < 4; mt++)
#pragma unroll
        for (int nt = 0; nt < 4; nt++)
#pragma unroll
            for (int e = 0; e < 4; e++) {
                int m = m0 + wm + mt * 16 + (lane >> 4) * 4 + e;
                int n = n0 + wn + nt * 16 + (lane & 15);
                int b = m >> 11, t = m & 2047;
                int h = n >> 6, d = n & 63;
                outp[((((size_t)b * 8 + h) * 2048 + t) << 6) + d] = f2bf(acc[mt][nt][e]);
            }
}

// ---------------- causal flash attention ----------------
// grid: (T/64, B*H). 4 waves; wave w owns queries qb*64+w*16 .. +15. BN=64 keys/iter.
__global__ __launch_bounds__(256) void k_flash(const ushort_t* __restrict__ qp,
                                               const ushort_t* __restrict__ kp,
                                               const ushort_t* __restrict__ vp,
                                               ushort_t* __restrict__ attn) {
    __shared__ __align__(16) ushort_t Ks[64 * 64];       // [key][d], swizzled
    __shared__ __align__(16) ushort_t Vt[64 * 72];       // [d][key], +8 pad
    __shared__ __align__(16) ushort_t Pl[4][16 * 72];    // per-wave P [16 q][64 key], +8 pad
    const int bh = blockIdx.y;
    const int qb = blockIdx.x;
    const int tid = threadIdx.x, wave = tid >> 6, lane = tid & 63;
    const int qw0 = qb * 64 + wave * 16;
    const size_t bh_off = (size_t)bh * 2048 * 64;

    bf16x8 qa[2];
    {
        const ushort_t* qrow = qp + bh_off + (size_t)(qw0 + (lane & 15)) * 64;
        qa[0] = *(const bf16x8*)(qrow + (lane >> 4) * 8);
        qa[1] = *(const bf16x8*)(qrow + 32 + (lane >> 4) * 8);
    }
    f32x4 o[4] = {};
    float m_run[4] = {-1e30f, -1e30f, -1e30f, -1e30f};
    float l_run[4] = {0.f, 0.f, 0.f, 0.f};

    for (int kb = 0; kb <= qb; ++kb) {
        const int kbase = kb * 64;
        __syncthreads();  // prior-iteration LDS reads done
        // stage K tile (8KB) via global_load_lds, swizzled source
#pragma unroll
        for (int i = 0; i < 2; i++) {
            int base = wave * 2048 + i * 1024;
            int bb = base + lane * 16;
            int row = bb >> 7;
            int sub = (bb >> 4) & 7;
            gload_lds16((const char*)(kp + bh_off + (size_t)(kbase + row) * 64) +
                            ((sub ^ (row & 7)) << 4),
                        (char*)Ks + base);
        }
        // stage V transposed: coalesced global read, scattered LDS write
#pragma unroll
        for (int it = 0; it < 2; ++it) {
            int t2 = tid + it * 256;
            int j = t2 >> 3;
            int d0 = (t2 & 7) * 8;
            bf16x8 vv = *(const bf16x8*)(vp + bh_off + (size_t)(kbase + j) * 64 + d0);
#pragma unroll
            for (int e = 0; e < 8; e++) Vt[(d0 + e) * 72 + j] = (ushort_t)vv[e];
        }
        __syncthreads();
        // S = Q K^T : FOUR 16x16 key tiles -> keys kbase + kt*16 + (lane&15), kt=0..3
        f32x4 s[4];
#pragma unroll
        for (int kt = 0; kt < 4; kt++) {
            f32x4 z = {};
#pragma unroll
            for (int ds = 0; ds < 2; ++ds) {
                int row = kt * 16 + (lane & 15);
                int sub = ds * 4 + (lane >> 4);
                bf16x8 kf = *(const bf16x8*)((const char*)Ks + row * 128 +
                                             ((sub ^ (row & 7)) << 4));
                z = MFMA16(qa[ds], kf, z);
            }
            s[kt] = z;
        }
        if (kb == qb) {  // diagonal block: causal mask
#pragma unroll
            for (int kt = 0; kt < 4; kt++)
#pragma unroll
                for (int e = 0; e < 4; e++) {
                    int key = kbase + kt * 16 + (lane & 15);
                    int qq = qw0 + (lane >> 4) * 4 + e;
                    if (key > qq) s[kt][e] = -1e30f;
                }
        }
        // online softmax (row q = qw0 + (lane>>4)*4 + e; reduce over 16-lane group x 4 tiles)
        float pv[4][4];  // [e][kt]
#pragma unroll
        for (int e = 0; e < 4; e++) {
            float mx = fmaxf(fmaxf(s[0][e], s[1][e]), fmaxf(s[2][e], s[3][e]));
            mx = fmaxf(mx, __shfl_xor(mx, 1));
            mx = fmaxf(mx, __shfl_xor(mx, 2));
            mx = fmaxf(mx, __shfl_xor(mx, 4));
            mx = fmaxf(mx, __shfl_xor(mx, 8));
            float mn = fmaxf(m_run[e], mx);
            float alpha = __expf(m_run[e] - mn);
            float rs = 0.f;
#pragma unroll
            for (int kt = 0; kt < 4; kt++) {
                float p = __expf(s[kt][e] - mn);
                pv[e][kt] = p;
                rs += p;
            }
            rs += __shfl_xor(rs, 1);
            rs += __shfl_xor(rs, 2);
            rs += __shfl_xor(rs, 4);
            rs += __shfl_xor(rs, 8);
            l_run[e] = l_run[e] * alpha + rs;
            m_run[e] = mn;
#pragma unroll
            for (int dt = 0; dt < 4; dt++) o[dt][e] *= alpha;
        }
        // P (C-layout, 16 q rows x 64 keys) -> LDS -> two K=32 A-fragments
        ushort_t* pw = &Pl[wave][0];
#pragma unroll
        for (int e = 0; e < 4; e++) {
            int row = (lane >> 4) * 4 + e;
#pragma unroll
            for (int kt = 0; kt < 4; kt++)
                pw[row * 72 + kt * 16 + (lane & 15)] = f2bf(pv[e][kt]);
        }
        asm volatile("s_waitcnt lgkmcnt(0)" ::: "memory");
        __builtin_amdgcn_sched_barrier(0);
        bf16x8 pa[2];
#pragma unroll
        for (int ks = 0; ks < 2; ks++)
            pa[ks] = *(const bf16x8*)(pw + (lane & 15) * 72 + ks * 32 + (lane >> 4) * 8);
#pragma unroll
        for (int dt = 0; dt < 4; dt++) {
            int drow = dt * 16 + (lane & 15);
#pragma unroll
            for (int ks = 0; ks < 2; ks++) {
                bf16x8 vf = *(const bf16x8*)(Vt + drow * 72 + ks * 32 + (lane >> 4) * 8);
                o[dt] = MFMA16(pa[ks], vf, o[dt]);
            }
        }
    }
    // epilogue: normalize and store to attn [B][T][H*D]
    const int b_ = bh >> 3, h_ = bh & 7;
#pragma unroll
    for (int e = 0; e < 4; e++) {
        float inv = 1.0f / l_run[e];
        int t = qw0 + (lane >> 4) * 4 + e;
        ushort_t* orow = attn + ((size_t)(b_ * 2048 + t) * 512) + h_ * 64;
#pragma unroll
        for (int dt = 0; dt < 4; dt++)
            orow[dt * 16 + (lane & 15)] = f2bf(o[dt][e] * inv);
    }
}

// ---------------- output projection GEMM + bias ----------------
__global__ __launch_bounds__(256) void k_gemm_proj(const ushort_t* __restrict__ attn,
                                                   const ushort_t* __restrict__ wp,
                                                   const float* __restrict__ bias,
                                                   float* __restrict__ out) {
    __shared__ __align__(16) ushort_t As[128 * 64];
    __shared__ __align__(16) ushort_t Bs[128 * 64];
    const int m0 = blockIdx.x * 128;
    const int n0 = blockIdx.y * 128;
    f32x4 acc[4][4] = {};
    gemm_tile_128<512>(attn, wp, m0, n0, As, Bs, acc);
    const int tid = threadIdx.x, wave = tid >> 6, lane = tid & 63;
    const int wm = (wave >> 1) * 64, wn = (wave & 1) * 64;
#pragma unroll
    for (int mt = 0; mt < 4; mt++)
#pragma unroll
        for (int nt = 0; nt < 4; nt++)
#pragma unroll
            for (int e = 0; e < 4; e++) {
                int m = m0 + wm + mt * 16 + (lane >> 4) * 4 + e;
                int n = n0 + wn + nt * 16 + (lane & 15);
                out[(size_t)m * 512 + n] = acc[mt][nt][e] + bias[n];
            }
}

// ---------------- launch ----------------
extern "C" void kernel_launch(void* const* d_in, const int* in_sizes, int n_in,
                              void* d_out, int out_size, void* d_ws, size_t ws_size,
                              hipStream_t stream) {
    const float* x = (const float*)d_in[0];
    const float* Wq = (const float*)d_in[1];
    const float* Wk = (const float*)d_in[2];
    const float* Wv = (const float*)d_in[3];
    const float* Wp = (const float*)d_in[4];
    const float* bp = (const float*)d_in[5];
    float* out = (float*)d_out;

    ushort_t* ws = (ushort_t*)d_ws;
    const size_t NX = (size_t)8 * 2048 * 512;  // 8388608 elements
    ushort_t* xb = ws;
    ushort_t* wqkv = xb + NX;
    ushort_t* wpj = wqkv + (size_t)3 * 512 * 512;
    ushort_t* q = wpj + (size_t)512 * 512;
    ushort_t* k = q + NX;
    ushort_t* v = k + NX;
    ushort_t* attn = xb;  // reuse: xb is dead after k_gemm_qkv (stream-serialized)

    hipLaunchKernelGGL(k_convert_x, dim3(4096), dim3(256), 0, stream, x, xb);
    hipLaunchKernelGGL(k_convert_w, dim3(4096), dim3(256), 0, stream, Wq, Wk, Wv, Wp, wqkv, wpj);
    hipLaunchKernelGGL(k_gemm_qkv, dim3(128, 12), dim3(256), 0, stream, xb, wqkv, q, k, v);
    hipLaunchKernelGGL(k_flash, dim3(32, 64), dim3(256), 0, stream, q, k, v, attn);
    hipLaunchKernelGGL(k_gemm_proj, dim3(128, 4), dim3(256), 0, stream, attn, wpj, bp, out);
}

// Round 5
// 307.843 us; speedup vs baseline: 1.4979x; 1.4979x over previous
//
#include <hip/hip_runtime.h>
#include <stdint.h>

// Pipeline: x(f32)->bf16; W->bf16 B^T layout (Wq pre-scaled by 1/8);
// QKV GEMM (MFMA 16x16x32 bf16, 128x128 tile, BK=64, global_load_lds + XOR swizzle);
// causal flash attention (BM=64/4 waves, BN=64 keys/iter, online softmax,
//   paired q-tiles for load balance, conflict-free V transpose staging);
// proj GEMM + bias -> f32 out.

typedef __attribute__((ext_vector_type(8))) short bf16x8;
typedef __attribute__((ext_vector_type(4))) float f32x4;
typedef unsigned short ushort_t;

#define MFMA16(a, b, c) __builtin_amdgcn_mfma_f32_16x16x32_bf16(a, b, c, 0, 0, 0)

__device__ __forceinline__ ushort_t f2bf(float x) {
    union { float f; uint32_t u; } v; v.f = x;
    uint32_t r = v.u + 0x7fffu + ((v.u >> 16) & 1u);
    return (ushort_t)(r >> 16);
}

__device__ __forceinline__ void gload_lds16(const void* g, void* l) {
    __builtin_amdgcn_global_load_lds(
        (const __attribute__((address_space(1))) unsigned int*)g,
        (__attribute__((address_space(3))) unsigned int*)l, 16, 0, 0);
}

// ---------------- convert kernels ----------------
__global__ __launch_bounds__(256) void k_convert_x(const float* __restrict__ x,
                                                   ushort_t* __restrict__ xb) {
    const size_t n = (size_t)8 * 2048 * 512;
    const size_t stride = (size_t)gridDim.x * 256 * 4;
    for (size_t i = ((size_t)blockIdx.x * 256 + threadIdx.x) * 4; i < n; i += stride) {
        float4 f = *(const float4*)(x + i);
        uint2 o;
        o.x = (uint32_t)f2bf(f.x) | ((uint32_t)f2bf(f.y) << 16);
        o.y = (uint32_t)f2bf(f.z) | ((uint32_t)f2bf(f.w) << 16);
        *(uint2*)(xb + i) = o;
    }
}

// wqkv[3][512][512]: row n=h*64+d, col k=c, B^T layout. wp[512][512]: wp[n][k]=Wproj[k][n].
__global__ __launch_bounds__(256) void k_convert_w(const float* __restrict__ Wq,
                                                   const float* __restrict__ Wk,
                                                   const float* __restrict__ Wv,
                                                   const float* __restrict__ Wp,
                                                   ushort_t* __restrict__ wqkv,
                                                   ushort_t* __restrict__ wp) {
    int i = blockIdx.x * 256 + threadIdx.x;  // 0 .. 1048575
    if (i < 3 * 512 * 512) {
        int which = i >> 18;
        int r = i & 262143;
        int n = r >> 9, k = r & 511;
        int h = n >> 6, d = n & 63;
        const float* W = which == 0 ? Wq : (which == 1 ? Wk : Wv);
        float val = W[((size_t)h * 512 + k) * 64 + d];
        if (which == 0) val *= 0.125f;  // fold 1/sqrt(D) into q
        wqkv[i] = f2bf(val);
    } else {
        int r = i - 3 * 512 * 512;
        int n = r >> 9, k = r & 511;
        wp[r] = f2bf(Wp[(size_t)k * 512 + n]);
    }
}

// ---------------- shared 128x128 GEMM tile (BK=64) ----------------
// A [M][K] row-major bf16, Bt [N][K] row-major bf16 (i.e. B transposed).
// LDS linear dest via global_load_lds; 16B-granule XOR swizzle (sub ^ (row&7)) applied
// on the GLOBAL source and again on the ds_read address (both-sides rule, catalog #21).
template <int KDIM>
__device__ __forceinline__ void gemm_tile_128(const ushort_t* __restrict__ A,
                                              const ushort_t* __restrict__ Bt,
                                              int m0, int n0,
                                              ushort_t* As, ushort_t* Bs,
                                              f32x4 (&acc)[4][4]) {
    const int tid = threadIdx.x;
    const int wave = tid >> 6, lane = tid & 63;
    const int wm = (wave >> 1) * 64, wn = (wave & 1) * 64;
    for (int k0 = 0; k0 < KDIM; k0 += 64) {
        __syncthreads();
#pragma unroll
        for (int i = 0; i < 4; i++) {
            int base = wave * 4096 + i * 1024;
            int bb = base + lane * 16;
            int row = bb >> 7;
            int sub = (bb >> 4) & 7;
            int swz = (sub ^ (row & 7)) << 4;
            gload_lds16((const char*)(A + (size_t)(m0 + row) * KDIM + k0) + swz,
                        (char*)As + base);
        }
#pragma unroll
        for (int i = 0; i < 4; i++) {
            int base = wave * 4096 + i * 1024;
            int bb = base + lane * 16;
            int row = bb >> 7;
            int sub = (bb >> 4) & 7;
            int swz = (sub ^ (row & 7)) << 4;
            gload_lds16((const char*)(Bt + (size_t)(n0 + row) * KDIM + k0) + swz,
                        (char*)Bs + base);
        }
        __syncthreads();
        bf16x8 af[4][2], bf[4][2];
#pragma unroll
        for (int mt = 0; mt < 4; mt++)
#pragma unroll
            for (int ks = 0; ks < 2; ks++) {
                int row = wm + mt * 16 + (lane & 15);
                int sub = ks * 4 + (lane >> 4);
                af[mt][ks] = *(const bf16x8*)((const char*)As + row * 128 +
                                              ((sub ^ (row & 7)) << 4));
            }
#pragma unroll
        for (int nt = 0; nt < 4; nt++)
#pragma unroll
            for (int ks = 0; ks < 2; ks++) {
                int row = wn + nt * 16 + (lane & 15);
                int sub = ks * 4 + (lane >> 4);
                bf[nt][ks] = *(const bf16x8*)((const char*)Bs + row * 128 +
                                              ((sub ^ (row & 7)) << 4));
            }
#pragma unroll
        for (int mt = 0; mt < 4; mt++)
#pragma unroll
            for (int nt = 0; nt < 4; nt++)
#pragma unroll
                for (int ks = 0; ks < 2; ks++)
                    acc[mt][nt] = MFMA16(af[mt][ks], bf[nt][ks], acc[mt][nt]);
    }
}

// ---------------- QKV projection GEMM ----------------
__global__ __launch_bounds__(256) void k_gemm_qkv(const ushort_t* __restrict__ xb,
                                                  const ushort_t* __restrict__ wqkv,
                                                  ushort_t* __restrict__ qo,
                                                  ushort_t* __restrict__ ko,
                                                  ushort_t* __restrict__ vo) {
    __shared__ __align__(16) ushort_t As[128 * 64];
    __shared__ __align__(16) ushort_t Bs[128 * 64];
    const int m0 = blockIdx.x * 128;
    const int n0g = blockIdx.y * 128;  // 0..1535
    f32x4 acc[4][4] = {};
    gemm_tile_128<512>(xb, wqkv, m0, n0g, As, Bs, acc);
    const int tid = threadIdx.x, wave = tid >> 6, lane = tid & 63;
    const int wm = (wave >> 1) * 64, wn = (wave & 1) * 64;
    const int which = n0g >> 9;
    ushort_t* outp = which == 0 ? qo : (which == 1 ? ko : vo);
    const int n0 = n0g & 511;
#pragma unroll
    for (int mt = 0; mt < 4; mt++)
#pragma unroll
        for (int nt = 0; nt < 4; nt++)
#pragma unroll
            for (int e = 0; e < 4; e++) {
                int m = m0 + wm + mt * 16 + (lane >> 4) * 4 + e;
                int n = n0 + wn + nt * 16 + (lane & 15);
                int b = m >> 11, t = m & 2047;
                int h = n >> 6, d = n & 63;
                outp[((((size_t)b * 8 + h) * 2048 + t) << 6) + d] = f2bf(acc[mt][nt][e]);
            }
}

// ---------------- causal flash attention ----------------
// grid: (16, B*H). Each block handles TWO q-tiles: qb=blockIdx.x and 31-blockIdx.x
// (33 K/V-tile iterations per block -> balanced load). 4 waves; wave w owns 16 q rows.
__global__ __launch_bounds__(256) void k_flash(const ushort_t* __restrict__ qp,
                                               const ushort_t* __restrict__ kp,
                                               const ushort_t* __restrict__ vp,
                                               ushort_t* __restrict__ attn) {
    __shared__ __align__(16) ushort_t Ks[64 * 64];       // [key][d], swizzled
    __shared__ __align__(16) ushort_t Vt[64 * 72];       // [d][key], +8 pad
    __shared__ __align__(16) ushort_t Pl[4][16 * 72];    // per-wave P [16 q][64 key], +8 pad
    const int bh = blockIdx.y;
    const int tid = threadIdx.x, wave = tid >> 6, lane = tid & 63;
    const size_t bh_off = (size_t)bh * 2048 * 64;
    const int b_ = bh >> 3, h_ = bh & 7;

    for (int p = 0; p < 2; ++p) {
        const int qb = (p == 0) ? blockIdx.x : (31 - blockIdx.x);
        const int qw0 = qb * 64 + wave * 16;

        bf16x8 qa[2];
        {
            const ushort_t* qrow = qp + bh_off + (size_t)(qw0 + (lane & 15)) * 64;
            qa[0] = *(const bf16x8*)(qrow + (lane >> 4) * 8);
            qa[1] = *(const bf16x8*)(qrow + 32 + (lane >> 4) * 8);
        }
        f32x4 o[4] = {};
        float m_run[4] = {-1e30f, -1e30f, -1e30f, -1e30f};
        float l_run[4] = {0.f, 0.f, 0.f, 0.f};

        for (int kb = 0; kb <= qb; ++kb) {
            const int kbase = kb * 64;
            __syncthreads();  // prior-iteration LDS reads done
            // stage K tile (8KB) via global_load_lds, swizzled source
#pragma unroll
            for (int i = 0; i < 2; i++) {
                int base = wave * 2048 + i * 1024;
                int bb = base + lane * 16;
                int row = bb >> 7;
                int sub = (bb >> 4) & 7;
                gload_lds16((const char*)(kp + bh_off + (size_t)(kbase + row) * 64) +
                                ((sub ^ (row & 7)) << 4),
                            (char*)Ks + base);
            }
            // stage V transposed: coalesced global read, rotated scatter write.
            // Rotation ee=(e+mm)&7 makes bank = 4*((e+mm)&7)+j/2 cover all 32 banks
            // per store instr (was: 16-way conflict with only 4 banks).
#pragma unroll
            for (int it = 0; it < 2; ++it) {
                int t2 = tid + it * 256;
                int j = t2 >> 3;
                int mm = t2 & 7;
                int d0 = mm * 8;
                bf16x8 vv = *(const bf16x8*)(vp + bh_off + (size_t)(kbase + j) * 64 + d0);
#pragma unroll
                for (int e = 0; e < 8; e++) {
                    int ee = (e + mm) & 7;
                    Vt[(d0 + ee) * 72 + j] = (ushort_t)vv[ee];
                }
            }
            __syncthreads();
            // S = Q K^T : FOUR 16x16 key tiles -> keys kbase + kt*16 + (lane&15)
            f32x4 s[4];
#pragma unroll
            for (int kt = 0; kt < 4; kt++) {
                f32x4 z = {};
#pragma unroll
                for (int ds = 0; ds < 2; ++ds) {
                    int row = kt * 16 + (lane & 15);
                    int sub = ds * 4 + (lane >> 4);
                    bf16x8 kf = *(const bf16x8*)((const char*)Ks + row * 128 +
                                                 ((sub ^ (row & 7)) << 4));
                    z = MFMA16(qa[ds], kf, z);
                }
                s[kt] = z;
            }
            if (kb == qb) {  // diagonal block: causal mask
#pragma unroll
                for (int kt = 0; kt < 4; kt++)
#pragma unroll
                    for (int e = 0; e < 4; e++) {
                        int key = kbase + kt * 16 + (lane & 15);
                        int qq = qw0 + (lane >> 4) * 4 + e;
                        if (key > qq) s[kt][e] = -1e30f;
                    }
            }
            // online softmax (row q = qw0 + (lane>>4)*4 + e; 16-lane-group reduce)
            float pv[4][4];  // [e][kt]
#pragma unroll
            for (int e = 0; e < 4; e++) {
                float mx = fmaxf(fmaxf(s[0][e], s[1][e]), fmaxf(s[2][e], s[3][e]));
                mx = fmaxf(mx, __shfl_xor(mx, 1));
                mx = fmaxf(mx, __shfl_xor(mx, 2));
                mx = fmaxf(mx, __shfl_xor(mx, 4));
                mx = fmaxf(mx, __shfl_xor(mx, 8));
                float mn = fmaxf(m_run[e], mx);
                float alpha = __expf(m_run[e] - mn);
                float rs = 0.f;
#pragma unroll
                for (int kt = 0; kt < 4; kt++) {
                    float pp = __expf(s[kt][e] - mn);
                    pv[e][kt] = pp;
                    rs += pp;
                }
                rs += __shfl_xor(rs, 1);
                rs += __shfl_xor(rs, 2);
                rs += __shfl_xor(rs, 4);
                rs += __shfl_xor(rs, 8);
                l_run[e] = l_run[e] * alpha + rs;
                m_run[e] = mn;
#pragma unroll
                for (int dt = 0; dt < 4; dt++) o[dt][e] *= alpha;
            }
            // P (C-layout, 16 q rows x 64 keys) -> LDS -> two K=32 A-fragments
            ushort_t* pw = &Pl[wave][0];
#pragma unroll
            for (int e = 0; e < 4; e++) {
                int row = (lane >> 4) * 4 + e;
#pragma unroll
                for (int kt = 0; kt < 4; kt++)
                    pw[row * 72 + kt * 16 + (lane & 15)] = f2bf(pv[e][kt]);
            }
            asm volatile("s_waitcnt lgkmcnt(0)" ::: "memory");
            __builtin_amdgcn_sched_barrier(0);
            bf16x8 pa[2];
#pragma unroll
            for (int ks = 0; ks < 2; ks++)
                pa[ks] = *(const bf16x8*)(pw + (lane & 15) * 72 + ks * 32 + (lane >> 4) * 8);
#pragma unroll
            for (int dt = 0; dt < 4; dt++) {
                int drow = dt * 16 + (lane & 15);
#pragma unroll
                for (int ks = 0; ks < 2; ks++) {
                    bf16x8 vf = *(const bf16x8*)(Vt + drow * 72 + ks * 32 + (lane >> 4) * 8);
                    o[dt] = MFMA16(pa[ks], vf, o[dt]);
                }
            }
        }
        // epilogue: normalize and store to attn [B][T][H*D]
#pragma unroll
        for (int e = 0; e < 4; e++) {
            float inv = 1.0f / l_run[e];
            int t = qw0 + (lane >> 4) * 4 + e;
            ushort_t* orow = attn + ((size_t)(b_ * 2048 + t) * 512) + h_ * 64;
#pragma unroll
            for (int dt = 0; dt < 4; dt++)
                orow[dt * 16 + (lane & 15)] = f2bf(o[dt][e] * inv);
        }
    }
}

// ---------------- output projection GEMM + bias ----------------
__global__ __launch_bounds__(256) void k_gemm_proj(const ushort_t* __restrict__ attn,
                                                   const ushort_t* __restrict__ wp,
                                                   const float* __restrict__ bias,
                                                   float* __restrict__ out) {
    __shared__ __align__(16) ushort_t As[128 * 64];
    __shared__ __align__(16) ushort_t Bs[128 * 64];
    const int m0 = blockIdx.x * 128;
    const int n0 = blockIdx.y * 128;
    f32x4 acc[4][4] = {};
    gemm_tile_128<512>(attn, wp, m0, n0, As, Bs, acc);
    const int tid = threadIdx.x, wave = tid >> 6, lane = tid & 63;
    const int wm = (wave >> 1) * 64, wn = (wave & 1) * 64;
#pragma unroll
    for (int mt = 0; mt < 4; mt++)
#pragma unroll
        for (int nt = 0; nt < 4; nt++)
#pragma unroll
            for (int e = 0; e < 4; e++) {
                int m = m0 + wm + mt * 16 + (lane >> 4) * 4 + e;
                int n = n0 + wn + nt * 16 + (lane & 15);
                out[(size_t)m * 512 + n] = acc[mt][nt][e] + bias[n];
            }
}

// ---------------- launch ----------------
extern "C" void kernel_launch(void* const* d_in, const int* in_sizes, int n_in,
                              void* d_out, int out_size, void* d_ws, size_t ws_size,
                              hipStream_t stream) {
    const float* x = (const float*)d_in[0];
    const float* Wq = (const float*)d_in[1];
    const float* Wk = (const float*)d_in[2];
    const float* Wv = (const float*)d_in[3];
    const float* Wp = (const float*)d_in[4];
    const float* bp = (const float*)d_in[5];
    float* out = (float*)d_out;

    ushort_t* ws = (ushort_t*)d_ws;
    const size_t NX = (size_t)8 * 2048 * 512;  // 8388608 elements
    ushort_t* xb = ws;
    ushort_t* wqkv = xb + NX;
    ushort_t* wpj = wqkv + (size_t)3 * 512 * 512;
    ushort_t* q = wpj + (size_t)512 * 512;
    ushort_t* k = q + NX;
    ushort_t* v = k + NX;
    ushort_t* attn = xb;  // reuse: xb is dead after k_gemm_qkv (stream-serialized)

    hipLaunchKernelGGL(k_convert_x, dim3(4096), dim3(256), 0, stream, x, xb);
    hipLaunchKernelGGL(k_convert_w, dim3(4096), dim3(256), 0, stream, Wq, Wk, Wv, Wp, wqkv, wpj);
    hipLaunchKernelGGL(k_gemm_qkv, dim3(128, 12), dim3(256), 0, stream, xb, wqkv, q, k, v);
    hipLaunchKernelGGL(k_flash, dim3(16, 64), dim3(256), 0, stream, q, k, v, attn);
    hipLaunchKernelGGL(k_gemm_proj, dim3(128, 4), dim3(256), 0, stream, attn, wpj, bp, out);
}

// Round 7
// 247.217 us; speedup vs baseline: 1.8652x; 1.2452x over previous
//
#include <hip/hip_runtime.h>
#include <stdint.h>

// Pipeline: x(f32)->bf16; W->bf16 B^T layout (Wq pre-scaled by 1/8);
// QKV GEMM (MFMA 16x16x32 bf16, 128x128 tile, BK=64, global_load_lds + XOR swizzle);
// causal flash attention (swapped QK^T, sigma-permuted K rows, in-register softmax,
//   zero P round-trip, paired q-tiles for load balance);
// proj GEMM + bias -> f32 out.

typedef __attribute__((ext_vector_type(8))) short bf16x8;
typedef __attribute__((ext_vector_type(4))) float f32x4;
typedef unsigned short ushort_t;

#define MFMA16(a, b, c) __builtin_amdgcn_mfma_f32_16x16x32_bf16(a, b, c, 0, 0, 0)

__device__ __forceinline__ ushort_t f2bf(float x) {
    union { float f; uint32_t u; } v; v.f = x;
    uint32_t r = v.u + 0x7fffu + ((v.u >> 16) & 1u);
    return (ushort_t)(r >> 16);
}

__device__ __forceinline__ uint32_t cvtpk_bf16(float lo, float hi) {
    uint32_t r;
    asm("v_cvt_pk_bf16_f32 %0, %1, %2" : "=v"(r) : "v"(lo), "v"(hi));
    return r;
}

__device__ __forceinline__ void gload_lds16(const void* g, void* l) {
    __builtin_amdgcn_global_load_lds(
        (const __attribute__((address_space(1))) unsigned int*)g,
        (__attribute__((address_space(3))) unsigned int*)l, 16, 0, 0);
}

// ---------------- convert kernels ----------------
__global__ __launch_bounds__(256) void k_convert_x(const float* __restrict__ x,
                                                   ushort_t* __restrict__ xb) {
    const size_t n = (size_t)8 * 2048 * 512;
    const size_t stride = (size_t)gridDim.x * 256 * 4;
    for (size_t i = ((size_t)blockIdx.x * 256 + threadIdx.x) * 4; i < n; i += stride) {
        float4 f = *(const float4*)(x + i);
        uint2 o;
        o.x = (uint32_t)f2bf(f.x) | ((uint32_t)f2bf(f.y) << 16);
        o.y = (uint32_t)f2bf(f.z) | ((uint32_t)f2bf(f.w) << 16);
        *(uint2*)(xb + i) = o;
    }
}

// wqkv[3][512][512]: row n=h*64+d, col k=c, B^T layout. wp[512][512]: wp[n][k]=Wproj[k][n].
__global__ __launch_bounds__(256) void k_convert_w(const float* __restrict__ Wq,
                                                   const float* __restrict__ Wk,
                                                   const float* __restrict__ Wv,
                                                   const float* __restrict__ Wp,
                                                   ushort_t* __restrict__ wqkv,
                                                   ushort_t* __restrict__ wp) {
    int i = blockIdx.x * 256 + threadIdx.x;  // 0 .. 1048575
    if (i < 3 * 512 * 512) {
        int which = i >> 18;
        int r = i & 262143;
        int n = r >> 9, k = r & 511;
        int h = n >> 6, d = n & 63;
        const float* W = which == 0 ? Wq : (which == 1 ? Wk : Wv);
        float val = W[((size_t)h * 512 + k) * 64 + d];
        if (which == 0) val *= 0.125f;  // fold 1/sqrt(D) into q
        wqkv[i] = f2bf(val);
    } else {
        int r = i - 3 * 512 * 512;
        int n = r >> 9, k = r & 511;
        wp[r] = f2bf(Wp[(size_t)k * 512 + n]);
    }
}

// ---------------- shared 128x128 GEMM tile (BK=64) ----------------
template <int KDIM>
__device__ __forceinline__ void gemm_tile_128(const ushort_t* __restrict__ A,
                                              const ushort_t* __restrict__ Bt,
                                              int m0, int n0,
                                              ushort_t* As, ushort_t* Bs,
                                              f32x4 (&acc)[4][4]) {
    const int tid = threadIdx.x;
    const int wave = tid >> 6, lane = tid & 63;
    const int wm = (wave >> 1) * 64, wn = (wave & 1) * 64;
    for (int k0 = 0; k0 < KDIM; k0 += 64) {
        __syncthreads();
#pragma unroll
        for (int i = 0; i < 4; i++) {
            int base = wave * 4096 + i * 1024;
            int bb = base + lane * 16;
            int row = bb >> 7;
            int sub = (bb >> 4) & 7;
            int swz = (sub ^ (row & 7)) << 4;
            gload_lds16((const char*)(A + (size_t)(m0 + row) * KDIM + k0) + swz,
                        (char*)As + base);
        }
#pragma unroll
        for (int i = 0; i < 4; i++) {
            int base = wave * 4096 + i * 1024;
            int bb = base + lane * 16;
            int row = bb >> 7;
            int sub = (bb >> 4) & 7;
            int swz = (sub ^ (row & 7)) << 4;
            gload_lds16((const char*)(Bt + (size_t)(n0 + row) * KDIM + k0) + swz,
                        (char*)Bs + base);
        }
        __syncthreads();
        bf16x8 af[4][2], bf[4][2];
#pragma unroll
        for (int mt = 0; mt < 4; mt++)
#pragma unroll
            for (int ks = 0; ks < 2; ks++) {
                int row = wm + mt * 16 + (lane & 15);
                int sub = ks * 4 + (lane >> 4);
                af[mt][ks] = *(const bf16x8*)((const char*)As + row * 128 +
                                              ((sub ^ (row & 7)) << 4));
            }
#pragma unroll
        for (int nt = 0; nt < 4; nt++)
#pragma unroll
            for (int ks = 0; ks < 2; ks++) {
                int row = wn + nt * 16 + (lane & 15);
                int sub = ks * 4 + (lane >> 4);
                bf[nt][ks] = *(const bf16x8*)((const char*)Bs + row * 128 +
                                              ((sub ^ (row & 7)) << 4));
            }
#pragma unroll
        for (int mt = 0; mt < 4; mt++)
#pragma unroll
            for (int nt = 0; nt < 4; nt++)
#pragma unroll
                for (int ks = 0; ks < 2; ks++)
                    acc[mt][nt] = MFMA16(af[mt][ks], bf[nt][ks], acc[mt][nt]);
    }
}

// ---------------- QKV projection GEMM ----------------
__global__ __launch_bounds__(256) void k_gemm_qkv(const ushort_t* __restrict__ xb,
                                                  const ushort_t* __restrict__ wqkv,
                                                  ushort_t* __restrict__ qo,
                                                  ushort_t* __restrict__ ko,
                                                  ushort_t* __restrict__ vo) {
    __shared__ __align__(16) ushort_t As[128 * 64];
    __shared__ __align__(16) ushort_t Bs[128 * 64];
    const int m0 = blockIdx.x * 128;
    const int n0g = blockIdx.y * 128;  // 0..1535
    f32x4 acc[4][4] = {};
    gemm_tile_128<512>(xb, wqkv, m0, n0g, As, Bs, acc);
    const int tid = threadIdx.x, wave = tid >> 6, lane = tid & 63;
    const int wm = (wave >> 1) * 64, wn = (wave & 1) * 64;
    const int which = n0g >> 9;
    ushort_t* outp = which == 0 ? qo : (which == 1 ? ko : vo);
    const int n0 = n0g & 511;
#pragma unroll
    for (int mt = 0; mt < 4; mt++)
#pragma unroll
        for (int nt = 0; nt < 4; nt++)
#pragma unroll
            for (int e = 0; e < 4; e++) {
                int m = m0 + wm + mt * 16 + (lane >> 4) * 4 + e;
                int n = n0 + wn + nt * 16 + (lane & 15);
                int b = m >> 11, t = m & 2047;
                int h = n >> 6, d = n & 63;
                outp[((((size_t)b * 8 + h) * 2048 + t) << 6) + d] = f2bf(acc[mt][nt][e]);
            }
}

// ---------------- causal flash attention (swapped QK^T, in-register softmax) ----
// grid: (16, B*H). Block handles q-tiles qb=blockIdx.x and 31-blockIdx.x (33 iters).
// 4 waves; wave owns 16 q rows. Per lane: q = qw0 + (lane&15); holds 16/64 keys.
// Tile t reads K rows sigma(t,m) = 32(t>>1) + 8(m>>2) + 4(t&1) + (m&3) so that
// lane (g=lane>>4) ends up holding keys 32ks+8g+j -- exactly the PV B-fragment.
// Ks swizzle: f(row) = 2*((row>>3)&3) + (row&1), applied both sides (rule #21).
__global__ __launch_bounds__(256) void k_flash(const ushort_t* __restrict__ qp,
                                               const ushort_t* __restrict__ kp,
                                               const ushort_t* __restrict__ vp,
                                               ushort_t* __restrict__ attn) {
    __shared__ __align__(16) ushort_t Ks[64 * 64];   // [key][d], f-swizzled
    __shared__ __align__(16) ushort_t Vt[64 * 72];   // [d][key], +8 pad
    const int bh = blockIdx.y;
    const int tid = threadIdx.x, wave = tid >> 6, lane = tid & 63;
    const int mq = lane & 15, g = lane >> 4;
    const size_t bh_off = (size_t)bh * 2048 * 64;
    const int b_ = bh >> 3, h_ = bh & 7;

    for (int p = 0; p < 2; ++p) {
        const int qb = (p == 0) ? blockIdx.x : (31 - blockIdx.x);
        const int qw0 = qb * 64 + wave * 16;
        const int qq = qw0 + mq;

        bf16x8 qa[2];
        {
            const ushort_t* qrow = qp + bh_off + (size_t)qq * 64;
            qa[0] = *(const bf16x8*)(qrow + g * 8);
            qa[1] = *(const bf16x8*)(qrow + 32 + g * 8);
        }
        f32x4 o[4] = {};
        float m_run = -1e30f, l_run = 0.f;

        for (int kb = 0; kb <= qb; ++kb) {
            const int kbase = kb * 64;
            __syncthreads();  // prior-iteration LDS reads done
            // stage K tile (8KB): linear LDS dest, f-swizzled global source
#pragma unroll
            for (int i = 0; i < 2; i++) {
                int base = wave * 2048 + i * 1024;
                int bb = base + lane * 16;
                int row = bb >> 7;
                int sub = (bb >> 4) & 7;
                int frow = (((row >> 3) & 3) << 1) | (row & 1);
                gload_lds16((const char*)(kp + bh_off + (size_t)(kbase + row) * 64) +
                                ((sub ^ frow) << 4),
                            (char*)Ks + base);
            }
            // stage V transposed: coalesced global read, rotated scatter write
#pragma unroll
            for (int it = 0; it < 2; ++it) {
                int t2 = tid + it * 256;
                int j = t2 >> 3;
                int mm = t2 & 7;
                int d0 = mm * 8;
                bf16x8 vv = *(const bf16x8*)(vp + bh_off + (size_t)(kbase + j) * 64 + d0);
#pragma unroll
                for (int e = 0; e < 8; e++) {
                    int ee = (e + mm) & 7;
                    Vt[(d0 + ee) * 72 + j] = (ushort_t)vv[ee];
                }
            }
            __syncthreads();
            // S^T = K Q^T : tile t covers keys sigma(t, .) ; lane holds
            // s[t][e] = S[q=qq][key = kbase + 32(t>>1) + 8g + 4(t&1) + e]
            f32x4 s[4];
#pragma unroll
            for (int t = 0; t < 4; t++) {
                int rs = ((t >> 1) << 5) + ((mq >> 2) << 3) + ((t & 1) << 2) + (mq & 3);
                int ft = (((rs >> 3) & 3) << 1) | (rs & 1);
                f32x4 z = {};
#pragma unroll
                for (int ds = 0; ds < 2; ++ds) {
                    bf16x8 kf = *(const bf16x8*)((const char*)Ks + rs * 128 +
                                                 (((ds * 4 + g) ^ ft) << 4));
                    z = MFMA16(kf, qa[ds], z);
                }
                s[t] = z;
            }
            if (kb == qb) {  // diagonal block: causal mask
#pragma unroll
                for (int t = 0; t < 4; t++)
#pragma unroll
                    for (int e = 0; e < 4; e++) {
                        int key = kbase + ((t >> 1) << 5) + (g << 3) + ((t & 1) << 2) + e;
                        if (key > qq) s[t][e] = -1e30f;
                    }
            }
            // in-register online softmax: one q-row per lane, 2 shuffles per reduce
            float mx = s[0][0];
#pragma unroll
            for (int t = 0; t < 4; t++)
#pragma unroll
                for (int e = 0; e < 4; e++) mx = fmaxf(mx, s[t][e]);
            mx = fmaxf(mx, __shfl_xor(mx, 16));
            mx = fmaxf(mx, __shfl_xor(mx, 32));
            float mn = fmaxf(m_run, mx);
            float alpha = __expf(m_run - mn);
            float pr[4][4];
            float rs_ = 0.f;
#pragma unroll
            for (int t = 0; t < 4; t++)
#pragma unroll
                for (int e = 0; e < 4; e++) {
                    float pp = __expf(s[t][e] - mn);
                    pr[t][e] = pp;
                    rs_ += pp;
                }
            rs_ += __shfl_xor(rs_, 16);
            rs_ += __shfl_xor(rs_, 32);
            l_run = l_run * alpha + rs_;
            m_run = mn;
#pragma unroll
            for (int dt = 0; dt < 4; dt++)
#pragma unroll
                for (int e = 0; e < 4; e++) o[dt][e] *= alpha;
            // P -> bf16 B-fragments in-register (no LDS, no shuffles)
            union { bf16x8 v; uint32_t u[4]; } pb[2];
#pragma unroll
            for (int ks = 0; ks < 2; ks++) {
                pb[ks].u[0] = cvtpk_bf16(pr[2 * ks][0], pr[2 * ks][1]);
                pb[ks].u[1] = cvtpk_bf16(pr[2 * ks][2], pr[2 * ks][3]);
                pb[ks].u[2] = cvtpk_bf16(pr[2 * ks + 1][0], pr[2 * ks + 1][1]);
                pb[ks].u[3] = cvtpk_bf16(pr[2 * ks + 1][2], pr[2 * ks + 1][3]);
            }
            // O^T += V^T P^T : o[dt][e] = O[q=qq][d = dt*16 + 4g + e]
#pragma unroll
            for (int dt = 0; dt < 4; dt++) {
                int drow = dt * 16 + mq;
#pragma unroll
                for (int ks = 0; ks < 2; ks++) {
                    bf16x8 vf = *(const bf16x8*)(Vt + drow * 72 + ks * 32 + g * 8);
                    o[dt] = MFMA16(vf, pb[ks].v, o[dt]);
                }
            }
        }
        // epilogue: normalize; lane owns row q=qq, 4 contiguous d per dt -> 8B stores
        float inv = 1.0f / l_run;
        ushort_t* orow = attn + ((size_t)(b_ * 2048 + qq) * 512) + h_ * 64;
#pragma unroll
        for (int dt = 0; dt < 4; dt++) {
            uint2 st;
            st.x = cvtpk_bf16(o[dt][0] * inv, o[dt][1] * inv);
            st.y = cvtpk_bf16(o[dt][2] * inv, o[dt][3] * inv);
            *(uint2*)(orow + dt * 16 + g * 4) = st;
        }
    }
}

// ---------------- output projection GEMM + bias ----------------
__global__ __launch_bounds__(256) void k_gemm_proj(const ushort_t* __restrict__ attn,
                                                   const ushort_t* __restrict__ wp,
                                                   const float* __restrict__ bias,
                                                   float* __restrict__ out) {
    __shared__ __align__(16) ushort_t As[128 * 64];
    __shared__ __align__(16) ushort_t Bs[128 * 64];
    const int m0 = blockIdx.x * 128;
    const int n0 = blockIdx.y * 128;
    f32x4 acc[4][4] = {};
    gemm_tile_128<512>(attn, wp, m0, n0, As, Bs, acc);
    const int tid = threadIdx.x, wave = tid >> 6, lane = tid & 63;
    const int wm = (wave >> 1) * 64, wn = (wave & 1) * 64;
#pragma unroll
    for (int mt = 0; mt < 4; mt++)
#pragma unroll
        for (int nt = 0; nt < 4; nt++)
#pragma unroll
            for (int e = 0; e < 4; e++) {
                int m = m0 + wm + mt * 16 + (lane >> 4) * 4 + e;
                int n = n0 + wn + nt * 16 + (lane & 15);
                out[(size_t)m * 512 + n] = acc[mt][nt][e] + bias[n];
            }
}

// ---------------- launch ----------------
extern "C" void kernel_launch(void* const* d_in, const int* in_sizes, int n_in,
                              void* d_out, int out_size, void* d_ws, size_t ws_size,
                              hipStream_t stream) {
    const float* x = (const float*)d_in[0];
    const float* Wq = (const float*)d_in[1];
    const float* Wk = (const float*)d_in[2];
    const float* Wv = (const float*)d_in[3];
    const float* Wp = (const float*)d_in[4];
    const float* bp = (const float*)d_in[5];
    float* out = (float*)d_out;

    ushort_t* ws = (ushort_t*)d_ws;
    const size_t NX = (size_t)8 * 2048 * 512;  // 8388608 elements
    ushort_t* xb = ws;
    ushort_t* wqkv = xb + NX;
    ushort_t* wpj = wqkv + (size_t)3 * 512 * 512;
    ushort_t* q = wpj + (size_t)512 * 512;
    ushort_t* k = q + NX;
    ushort_t* v = k + NX;
    ushort_t* attn = xb;  // reuse: xb is dead after k_gemm_qkv (stream-serialized)

    hipLaunchKernelGGL(k_convert_x, dim3(4096), dim3(256), 0, stream, x, xb);
    hipLaunchKernelGGL(k_convert_w, dim3(4096), dim3(256), 0, stream, Wq, Wk, Wv, Wp, wqkv, wpj);
    hipLaunchKernelGGL(k_gemm_qkv, dim3(128, 12), dim3(256), 0, stream, xb, wqkv, q, k, v);
    hipLaunchKernelGGL(k_flash, dim3(16, 64), dim3(256), 0, stream, q, k, v, attn);
    hipLaunchKernelGGL(k_gemm_proj, dim3(128, 4), dim3(256), 0, stream, attn, wpj, bp, out);
}